// Round 1
// baseline (46.216 us; speedup 1.0000x reference)
//
#include <hip/hip_runtime.h>

#define NF 39
#define NE 40
#define NP 741      // 39*38/2
#define NB 4096
#define LST 44      // padded LDS row stride in floats (16B-aligned, breaks bank periodicity)

// ---------------- Kernel 1: per-sample gather + pairwise dots ----------------
__global__ __launch_bounds__(256) void fm_k1(
    const int* __restrict__ inputs, const int* __restrict__ rows,
    const int* __restrict__ cols, const float* __restrict__ w,
    const float* __restrict__ v, float* __restrict__ level2,
    float* __restrict__ lsum)
{
    __shared__ float xv[NF * LST];
    __shared__ int   idx[NF];
    const int b = blockIdx.x;
    const int t = threadIdx.x;

    if (t < NF) idx[t] = inputs[b * NF + t];
    __syncthreads();

    // gather 39 rows x 40 floats = 390 float4 loads (v rows are 160B, 16B aligned)
    for (int q = t; q < NF * (NE / 4); q += 256) {
        const int r = q / (NE / 4), o = q % (NE / 4);
        const float4 val = *reinterpret_cast<const float4*>(v + (size_t)idx[r] * NE + o * 4);
        *reinterpret_cast<float4*>(&xv[r * LST + o * 4]) = val;
    }

    // first-order term: sum of w[idx[f]] over 39 features (wave 0 only)
    if (t < 64) {
        float wv = (t < NF) ? w[idx[t]] : 0.0f;
#pragma unroll
        for (int o = 32; o > 0; o >>= 1) wv += __shfl_down(wv, o, 64);
        if (t == 0) lsum[b] = wv;
    }
    __syncthreads();

    float* outrow = level2 + (size_t)b * NP;
    for (int p = t; p < NP; p += 256) {
        const float* A = &xv[rows[p] * LST];
        const float* C = &xv[cols[p] * LST];
        float acc = 0.0f;
#pragma unroll
        for (int e = 0; e < NE; e += 4) {
            const float4 av = *reinterpret_cast<const float4*>(A + e);
            const float4 cv = *reinterpret_cast<const float4*>(C + e);
            acc = fmaf(av.x, cv.x, acc);
            acc = fmaf(av.y, cv.y, acc);
            acc = fmaf(av.z, cv.z, acc);
            acc = fmaf(av.w, cv.w, acc);
        }
        outrow[p] = acc;
    }
}

// ---------------- Kernel 2: per-pair batch statistics ----------------
__global__ __launch_bounds__(256) void fm_k2(
    const float* __restrict__ level2, const float* __restrict__ ew,
    float* __restrict__ mean, float* __restrict__ scale)
{
    const int p = blockIdx.x;
    const int t = threadIdx.x;
    float sum = 0.0f, sq = 0.0f;
    for (int b = t; b < NB; b += 256) {
        const float x = level2[(size_t)b * NP + p];
        sum += x;
        sq = fmaf(x, x, sq);
    }
    __shared__ float s1[4], s2[4];
#pragma unroll
    for (int o = 32; o > 0; o >>= 1) {
        sum += __shfl_down(sum, o, 64);
        sq  += __shfl_down(sq,  o, 64);
    }
    const int wid = t >> 6, lane = t & 63;
    if (lane == 0) { s1[wid] = sum; s2[wid] = sq; }
    __syncthreads();
    if (t == 0) {
        sum = s1[0] + s1[1] + s1[2] + s1[3];
        sq  = s2[0] + s2[1] + s2[2] + s2[3];
        const float m   = sum * (1.0f / NB);
        const float var = sq * (1.0f / NB) - m * m;
        mean[p]  = m;
        scale[p] = ew[p] * rsqrtf(var + 1.0e-3f);
    }
}

// ---------------- Kernel 3: normalize + reduce + first-order ----------------
__global__ __launch_bounds__(256) void fm_k3(
    const float* __restrict__ level2, const float* __restrict__ lsum,
    const float* __restrict__ mean, const float* __restrict__ scale,
    const float* __restrict__ bias, float* __restrict__ out)
{
    const int b = blockIdx.x;
    const int t = threadIdx.x;
    const float* row = level2 + (size_t)b * NP;
    float acc = 0.0f;
    for (int p = t; p < NP; p += 256) {
        acc += (row[p] - mean[p]) * scale[p];
    }
    __shared__ float s1[4];
#pragma unroll
    for (int o = 32; o > 0; o >>= 1) acc += __shfl_down(acc, o, 64);
    if ((t & 63) == 0) s1[t >> 6] = acc;
    __syncthreads();
    if (t == 0) out[b] = lsum[b] + (s1[0] + s1[1] + s1[2] + s1[3]) + bias[0];
}

extern "C" void kernel_launch(void* const* d_in, const int* in_sizes, int n_in,
                              void* d_out, int out_size, void* d_ws, size_t ws_size,
                              hipStream_t stream)
{
    const int*   inputs = (const int*)  d_in[0];
    const int*   rows   = (const int*)  d_in[1];
    const int*   cols   = (const int*)  d_in[2];
    const float* w      = (const float*)d_in[3];
    const float* v      = (const float*)d_in[4];
    const float* bias   = (const float*)d_in[5];
    const float* ew     = (const float*)d_in[6];
    float*       out    = (float*)      d_out;

    // workspace layout (floats): level2[NB*NP] | lsum[NB] | mean[NP] | scale[NP]
    float* level2 = (float*)d_ws;
    float* lsum   = level2 + (size_t)NB * NP;
    float* mean   = lsum + NB;
    float* scale  = mean + NP;

    fm_k1<<<NB, 256, 0, stream>>>(inputs, rows, cols, w, v, level2, lsum);
    fm_k2<<<NP, 256, 0, stream>>>(level2, ew, mean, scale);
    fm_k3<<<NB, 256, 0, stream>>>(level2, lsum, mean, scale, bias, out);
}